// Round 8
// baseline (482.942 us; speedup 1.0000x reference)
//
#include <hip/hip_runtime.h>
#include <hip/hip_bf16.h>
#include <math.h>

#define B_SZc    4
#define L_SEQc   4096
#define EPSc     1e-6f
#define CHUNKc   128
#define NCHUNKc  32

// per-batch element counts
#define QKV_PER_B  4194304ull        // 16*4096*64
#define ATT_PER_B  4194304ull
#define X_PER_B    4194304ull
#define S_PER_B    2097152ull        // 16*32*64*64
#define Z_PER_B    32768ull

typedef __attribute__((ext_vector_type(8))) short s16x8;
typedef __attribute__((ext_vector_type(4))) short s16x4;
typedef __attribute__((ext_vector_type(4))) float f32x4;

__device__ __forceinline__ float phi_f(float x) {
    return x > 0.0f ? x + 1.0f : expf(x);   // elu(x)+1
}
__device__ __forceinline__ float bf2f(short h) {
    return __uint_as_float(((unsigned int)(unsigned short)h) << 16);
}
__device__ __forceinline__ short f2bf(float f) {
    unsigned int u = __float_as_uint(f);
    u = (u + 0x7FFFu + ((u >> 16) & 1u)) >> 16;   // RNE
    return (short)u;
}

#define GLOAD16(ldsp, gp) \
    __builtin_amdgcn_global_load_lds((const __attribute__((address_space(1))) void*)(gp), \
                                     (__attribute__((address_space(3))) void*)(ldsp), 16, 0, 0)

// ---------------------------------------------------------------------------
__global__ __launch_bounds__(256)
void cvt_f32_bf16(const float* __restrict__ in, short* __restrict__ out, int n)
{
    int i = (blockIdx.x * 256 + threadIdx.x) * 4;
    const int stride = gridDim.x * 256 * 4;
    for (; i < n; i += stride) {
        float4 v = *(const float4*)(in + i);
        short4 o = {f2bf(v.x), f2bf(v.y), f2bf(v.z), f2bf(v.w)};
        *(short4*)(out + i) = o;
    }
}

// ---------------------------------------------------------------------------
// bf16 MFMA GEMM NT (m97 structure) + XCD-swizzled block order.
// MODE 0: C fp32 row-major. MODE 1: qkv scatter via LDS-staged epilogue:
//   q row-major (phi), k row-major + transposed (phi), v transposed only.
// ---------------------------------------------------------------------------
template<int MODE>
__global__ __launch_bounds__(256)
void gemm_bf16(const short* __restrict__ A, const short* __restrict__ Bm,
               int M, int N, int K, float* __restrict__ C,
               short* __restrict__ qb, short* __restrict__ kb,
               short* __restrict__ kTb, short* __restrict__ vTb)
{
    __shared__ __align__(16) short smem[8192];   // 16 KB: lA | lB, reused by epilogue
    short* lA = smem;
    short* lB = smem + 4096;

    const int tid = threadIdx.x;
    const int lane = tid & 63;
    const int wave = tid >> 6;
    const int wr = wave >> 1, wc = wave & 1;

    // XCD-aware bijective swizzle (nwg % 8 == 0 for all our grids)
    int flat = blockIdx.y * gridDim.x + blockIdx.x;
    const int nwg = gridDim.x * gridDim.y;
    flat = (flat & 7) * (nwg >> 3) + (flat >> 3);
    const int bm = flat / gridDim.x;
    const int bn = flat % gridDim.x;

    const short* Abase = A + (size_t)bm * 128 * K;
    const short* Bbase = Bm + (size_t)bn * 128 * K;

    f32x4 acc[4][4];
#pragma unroll
    for (int i = 0; i < 4; ++i)
#pragma unroll
        for (int j = 0; j < 4; ++j) acc[i][j] = (f32x4){0.f, 0.f, 0.f, 0.f};

    const int lr = lane & 15;
    const int lk = (lane >> 4) * 8;
    const int cr0 = (lane >> 4) * 4;

    for (int k0 = 0; k0 < K; k0 += 32) {
#pragma unroll
        for (int c2 = 0; c2 < 2; ++c2) {
            const int idx = c2 * 256 + tid;
            const int row = idx >> 2;
            const int ks  = (idx & 3) * 8;
            GLOAD16(&lA[idx * 8], Abase + (size_t)row * K + k0 + ks);
            GLOAD16(&lB[idx * 8], Bbase + (size_t)row * K + k0 + ks);
        }
        __syncthreads();
        s16x8 af[4], bf[4];
#pragma unroll
        for (int m = 0; m < 4; ++m)
            af[m] = *(const s16x8*)&lA[(wr * 64 + m * 16 + lr) * 32 + lk];
#pragma unroll
        for (int n = 0; n < 4; ++n)
            bf[n] = *(const s16x8*)&lB[(wc * 64 + n * 16 + lr) * 32 + lk];
#pragma unroll
        for (int m = 0; m < 4; ++m)
#pragma unroll
            for (int n = 0; n < 4; ++n)
                acc[m][n] = __builtin_amdgcn_mfma_f32_16x16x32_bf16(af[m], bf[n], acc[m][n], 0, 0, 0);
        __syncthreads();
    }

    if (MODE == 0) {
#pragma unroll
        for (int m = 0; m < 4; ++m)
#pragma unroll
            for (int n = 0; n < 4; ++n) {
                const int col = bn * 128 + wc * 64 + n * 16 + lr;
#pragma unroll
                for (int j = 0; j < 4; ++j) {
                    const int row = bm * 128 + wr * 64 + m * 16 + cr0 + j;
                    C[(size_t)row * N + col] = acc[m][n][j];
                }
            }
    } else {
        // -------- LDS-staged scatter epilogue --------
        const int which = bn >> 3;             // 0=q, 1=k, 2=v (uniform per block)
        const int b = bm >> 5;                 // pass-local batch
        const int l_base = (bm & 31) * 128;
        short (*eps)[33] = (short(*)[33])smem; // 128 x 33 shorts = 8448 B < 16 KB

        for (int g = 0; g < 4; ++g) {          // 4 column-groups of 32
            __syncthreads();                   // prior reads done / K-loop done
            if (wc == (g >> 1)) {
                const int subn = (g & 1) * 2;
#pragma unroll
                for (int nn = 0; nn < 2; ++nn) {
                    const int n = subn + nn;
                    const int lc = nn * 16 + lr;
#pragma unroll
                    for (int m = 0; m < 4; ++m)
#pragma unroll
                        for (int j = 0; j < 4; ++j) {
                            float v = acc[m][n][j];
                            if (which < 2) v = phi_f(v);
                            eps[wr * 64 + m * 16 + cr0 + j][lc] = f2bf(v);
                        }
                }
            }
            __syncthreads();
            const int gcol = bn * 128 + g * 32;
            const int h = (gcol >> 6) & 15;
            const int d_base = gcol & 63;      // 0 or 32
            const size_t bh = (size_t)(b * 16 + h);
            if (which < 2) {
                short* dst0 = (which == 0) ? qb : kb;
                const int r = tid >> 2, q4 = tid & 3;
#pragma unroll
                for (int it = 0; it < 2; ++it) {
                    const int rr = r + it * 64;
                    s16x8 vv;
#pragma unroll
                    for (int i = 0; i < 8; ++i) vv[i] = eps[rr][q4 * 8 + i];
                    *(s16x8*)(dst0 + (bh * 4096 + l_base + rr) * 64 + d_base + q4 * 8) = vv;
                }
            }
            if (which >= 1) {
                short* dstT = (which == 1) ? kTb : vTb;
                const int dl = tid >> 4, ls = tid & 15;
#pragma unroll
                for (int it = 0; it < 2; ++it) {
                    const int dd = dl + it * 16;
                    s16x8 vv;
#pragma unroll
                    for (int i = 0; i < 8; ++i) vv[i] = eps[ls * 8 + i][dd];
                    *(s16x8*)(dstT + (bh * 64 + d_base + dd) * 4096 + l_base + ls * 8) = vv;
                }
            }
        }
    }
}

// ---------------------------------------------------------------------------
// Phase A (MFMA): per (bh, chunk): ST[e][d] = sum_t v[t][e]*k[t][d]; z[d].
// ---------------------------------------------------------------------------
__global__ __launch_bounds__(256)
void chunk_kv(const short* __restrict__ kTb, const short* __restrict__ vTb,
              float* __restrict__ ST, float* __restrict__ z)
{
    const int wave = threadIdx.x >> 6;
    const int lane = threadIdx.x & 63;
    const int c = blockIdx.x * 4 + wave;
    const int bh = blockIdx.y;
    const short* kT = kTb + (size_t)bh * 64 * 4096 + c * CHUNKc;
    const short* vT = vTb + (size_t)bh * 64 * 4096 + c * CHUNKc;
    const int lr = lane & 15;
    const int lk = (lane >> 4) * 8;

    f32x4 acc[4][4];
    f32x4 accz[4];
#pragma unroll
    for (int m = 0; m < 4; ++m) {
        accz[m] = (f32x4){0.f, 0.f, 0.f, 0.f};
#pragma unroll
        for (int n = 0; n < 4; ++n) acc[m][n] = (f32x4){0.f, 0.f, 0.f, 0.f};
    }
    s16x8 ones;
#pragma unroll
    for (int j = 0; j < 8; ++j) ones[j] = (short)0x3F80;

#pragma unroll
    for (int ks = 0; ks < 4; ++ks) {
        const int t0 = ks * 32 + lk;
        s16x8 a[4], b[4];
#pragma unroll
        for (int m = 0; m < 4; ++m)
            a[m] = *(const s16x8*)(vT + (size_t)(m * 16 + lr) * 4096 + t0);
#pragma unroll
        for (int n = 0; n < 4; ++n)
            b[n] = *(const s16x8*)(kT + (size_t)(n * 16 + lr) * 4096 + t0);
#pragma unroll
        for (int m = 0; m < 4; ++m)
#pragma unroll
            for (int n = 0; n < 4; ++n)
                acc[m][n] = __builtin_amdgcn_mfma_f32_16x16x32_bf16(a[m], b[n], acc[m][n], 0, 0, 0);
#pragma unroll
        for (int n = 0; n < 4; ++n)
            accz[n] = __builtin_amdgcn_mfma_f32_16x16x32_bf16(ones, b[n], accz[n], 0, 0, 0);
    }

    float* STc = ST + ((size_t)bh * NCHUNKc + c) * 4096;
    const int er0 = (lane >> 4) * 4;
#pragma unroll
    for (int m = 0; m < 4; ++m)
#pragma unroll
        for (int n = 0; n < 4; ++n)
#pragma unroll
            for (int j = 0; j < 4; ++j)
                STc[(m * 16 + er0 + j) * 64 + n * 16 + lr] = acc[m][n][j];
    if (lane < 16) {
        float* zc = z + ((size_t)bh * NCHUNKc + c) * 64;
#pragma unroll
        for (int n = 0; n < 4; ++n) zc[n * 16 + lane] = accz[n][0];
    }
}

// ---------------------------------------------------------------------------
__global__ __launch_bounds__(256)
void prefix_chunks(float* __restrict__ ST, float* __restrict__ z)
{
    const int sec = blockIdx.x, bh = blockIdx.y;
    const int tid = threadIdx.x;
    if (sec < 16) {
        float* base = ST + (size_t)bh * NCHUNKc * 4096 + sec * 256 + tid;
        float acc = 0.0f;
#pragma unroll
        for (int c = 0; c < NCHUNKc; ++c) {
            float t = base[(size_t)c * 4096];
            base[(size_t)c * 4096] = acc;
            acc += t;
        }
    } else if (tid < 64) {
        float* base = z + (size_t)bh * NCHUNKc * 64 + tid;
        float acc = 0.0f;
#pragma unroll
        for (int c = 0; c < NCHUNKc; ++c) {
            float t = base[c * 64];
            base[c * 64] = acc;
            acc += t;
        }
    }
}

// ---------------------------------------------------------------------------
// Phase C (MFMA): P = causal(QK^T) -> LDS fp32; den = rowsum(P)+q.z_pre;
// num = P@V + Q@(S_hi+S_lo); att = num/den.
// ---------------------------------------------------------------------------
__global__ __launch_bounds__(256)
void chunk_out(const short* __restrict__ qb, const short* __restrict__ kb,
               const short* __restrict__ vTb, const float* __restrict__ ST,
               const float* __restrict__ z, short* __restrict__ attb)
{
    const int c = blockIdx.x, bh = blockIdx.y;
    const int b = bh >> 4, h = bh & 15;
    const short* qc = qb + ((size_t)bh * L_SEQc + c * CHUNKc) * 64;
    const short* kc = kb + ((size_t)bh * L_SEQc + c * CHUNKc) * 64;
    const short* vT = vTb + (size_t)bh * 64 * 4096 + c * CHUNKc;
    const float* STp = ST + ((size_t)bh * NCHUNKc + c) * 4096;
    const float* zp  = z + ((size_t)bh * NCHUNKc + c) * 64;

    __shared__ float P[128][130];
    __shared__ float den_s[128];

    const int tid = threadIdx.x;
    const int lane = tid & 63;
    const int wave = tid >> 6;
    const int wr = wave >> 1, wc = wave & 1;
    const int lr = lane & 15;
    const int lg = lane >> 4;
    const int lk = lg * 8;
    const int cr0 = lg * 4;

    // ---- Phase 1: P = QK^T, causal mask, fp32 -> LDS ----
    {
        f32x4 p[4][4];
#pragma unroll
        for (int m = 0; m < 4; ++m)
#pragma unroll
            for (int n = 0; n < 4; ++n) p[m][n] = (f32x4){0.f, 0.f, 0.f, 0.f};
#pragma unroll
        for (int ks = 0; ks < 2; ++ks) {
            s16x8 a[4], bfr[4];
#pragma unroll
            for (int m = 0; m < 4; ++m)
                a[m] = *(const s16x8*)(qc + (size_t)(wr * 64 + m * 16 + lr) * 64 + ks * 32 + lk);
#pragma unroll
            for (int n = 0; n < 4; ++n)
                bfr[n] = *(const s16x8*)(kc + (size_t)(wc * 64 + n * 16 + lr) * 64 + ks * 32 + lk);
#pragma unroll
            for (int m = 0; m < 4; ++m)
#pragma unroll
                for (int n = 0; n < 4; ++n)
                    p[m][n] = __builtin_amdgcn_mfma_f32_16x16x32_bf16(a[m], bfr[n], p[m][n], 0, 0, 0);
        }
#pragma unroll
        for (int m = 0; m < 4; ++m)
#pragma unroll
            for (int n = 0; n < 4; ++n) {
                const int cc = wc * 64 + n * 16 + lr;
#pragma unroll
                for (int j = 0; j < 4; ++j) {
                    const int r = wr * 64 + m * 16 + cr0 + j;
                    P[r][cc] = (cc <= r) ? p[m][n][j] : 0.0f;
                }
            }
    }
    __syncthreads();

    // ---- Phase 2: den ----
    {
        const int r = tid >> 1;
        const int half = tid & 1;
        float s = 0.0f;
        const float* Pr = &P[r][half * 64];
#pragma unroll
        for (int t = 0; t < 64; t += 2) {
            float2 v2 = *(const float2*)&Pr[t];
            s += v2.x + v2.y;
        }
        const short* qr = qc + r * 64 + half * 32;
        const float* zh = zp + half * 32;
#pragma unroll
        for (int d0 = 0; d0 < 32; d0 += 8) {
            s16x8 qv = *(const s16x8*)(qr + d0);
#pragma unroll
            for (int j = 0; j < 8; ++j) s += bf2f(qv[j]) * zh[d0 + j];
        }
        s += __shfl_xor(s, 1);
        if (half == 0) den_s[r] = fmaxf(s, EPSc);
    }
    __syncthreads();

    // ---- Phase 3: num = P @ V^T + Q @ (S_hi + S_lo) ----
    f32x4 num[4][2];
#pragma unroll
    for (int m = 0; m < 4; ++m)
#pragma unroll
        for (int n = 0; n < 2; ++n) num[m][n] = (f32x4){0.f, 0.f, 0.f, 0.f};

#pragma unroll
    for (int ks = 0; ks < 4; ++ks) {
        const int t0 = ks * 32 + lk;
        s16x8 a[4];
#pragma unroll
        for (int m = 0; m < 4; ++m) {
            const float* pr = &P[wr * 64 + m * 16 + lr][t0];
            float2 f0 = *(const float2*)&pr[0];
            float2 f1 = *(const float2*)&pr[2];
            float2 f2 = *(const float2*)&pr[4];
            float2 f3 = *(const float2*)&pr[6];
            s16x8 av;
            av[0] = f2bf(f0.x); av[1] = f2bf(f0.y);
            av[2] = f2bf(f1.x); av[3] = f2bf(f1.y);
            av[4] = f2bf(f2.x); av[5] = f2bf(f2.y);
            av[6] = f2bf(f3.x); av[7] = f2bf(f3.y);
            a[m] = av;
        }
#pragma unroll
        for (int n = 0; n < 2; ++n) {
            s16x8 bv = *(const s16x8*)(vT + (size_t)(wc * 32 + n * 16 + lr) * 4096 + t0);
#pragma unroll
            for (int m = 0; m < 4; ++m)
                num[m][n] = __builtin_amdgcn_mfma_f32_16x16x32_bf16(a[m], bv, num[m][n], 0, 0, 0);
        }
    }

#pragma unroll
    for (int kk = 0; kk < 2; ++kk) {
        s16x8 qa[4];
#pragma unroll
        for (int m = 0; m < 4; ++m)
            qa[m] = *(const s16x8*)(qc + (size_t)(wr * 64 + m * 16 + lr) * 64 + kk * 32 + lk);
#pragma unroll
        for (int n = 0; n < 2; ++n) {
            const float* sp = STp + (size_t)(wc * 32 + n * 16 + lr) * 64 + kk * 32 + lk;
            float4 s0 = *(const float4*)sp;
            float4 s1 = *(const float4*)(sp + 4);
            float sv[8] = {s0.x, s0.y, s0.z, s0.w, s1.x, s1.y, s1.z, s1.w};
            s16x8 bhi, blo;
#pragma unroll
            for (int j = 0; j < 8; ++j) {
                short hi = f2bf(sv[j]);
                bhi[j] = hi;
                blo[j] = f2bf(sv[j] - bf2f(hi));
            }
#pragma unroll
            for (int m = 0; m < 4; ++m) {
                num[m][n] = __builtin_amdgcn_mfma_f32_16x16x32_bf16(qa[m], bhi, num[m][n], 0, 0, 0);
                num[m][n] = __builtin_amdgcn_mfma_f32_16x16x32_bf16(qa[m], blo, num[m][n], 0, 0, 0);
            }
        }
    }

#pragma unroll
    for (int m = 0; m < 4; ++m)
#pragma unroll
        for (int n = 0; n < 2; ++n) {
            const int e = wc * 32 + n * 16 + lr;
#pragma unroll
            for (int j = 0; j < 4; ++j) {
                const int r = wr * 64 + m * 16 + cr0 + j;
                const float inv = 1.0f / den_s[r];
                attb[((size_t)(b * 4096 + c * CHUNKc + r)) * 1024 + h * 64 + e] =
                    f2bf(num[m][n][j] * inv);
            }
        }
}

// ---------------------------------------------------------------------------
extern "C" void kernel_launch(void* const* d_in, const int* in_sizes, int n_in,
                              void* d_out, int out_size, void* d_ws, size_t ws_size,
                              hipStream_t stream) {
    const float* x     = (const float*)d_in[0];
    const float* w_qkv = (const float*)d_in[1];
    const float* w_out = (const float*)d_in[2];
    float* out = (float*)d_out;

    const size_t fixedB = 2ull * (3072 * 1024 + 1024 * 1024);
    const size_t perB_real = 2ull * X_PER_B + 2ull * 4 * QKV_PER_B + 2ull * ATT_PER_B
                           + 4ull * S_PER_B + 4ull * Z_PER_B;
    int Bp = 1;
    if (ws_size >= fixedB + 4 * perB_real + 65536) Bp = 4;
    else if (ws_size >= fixedB + 2 * perB_real + 65536) Bp = 2;

    char* p = (char*)d_ws;
    short* wqkvb = (short*)p; p += 2ull * 3072 * 1024;
    short* woutb = (short*)p; p += 2ull * 1024 * 1024;
    short* xb    = (short*)p; p += 2ull * X_PER_B * Bp;
    short* qb    = (short*)p; p += 2ull * QKV_PER_B * Bp;
    short* kb    = (short*)p; p += 2ull * QKV_PER_B * Bp;
    short* kTb   = (short*)p; p += 2ull * QKV_PER_B * Bp;
    short* vTb   = (short*)p; p += 2ull * QKV_PER_B * Bp;
    short* attb  = (short*)p; p += 2ull * ATT_PER_B * Bp;
    float* S     = (float*)p; p += 4ull * S_PER_B * Bp;
    float* z     = (float*)p;

    const int Mp = Bp * 4096;
    const int BHp = Bp * 16;

    cvt_f32_bf16<<<dim3(1024), 256, 0, stream>>>(w_qkv, wqkvb, 3072 * 1024);
    cvt_f32_bf16<<<dim3(512), 256, 0, stream>>>(w_out, woutb, 1024 * 1024);

    for (int b0 = 0; b0 < B_SZc; b0 += Bp) {
        const float* xp = x + (size_t)b0 * 4096 * 1024;

        cvt_f32_bf16<<<dim3(2048), 256, 0, stream>>>(xp, xb, Mp * 1024);

        // 1) QKV projection + phi + scatter (q, k, kT, vT)
        dim3 g1(3072 / 128, Mp / 128);
        gemm_bf16<1><<<g1, 256, 0, stream>>>(xb, wqkvb, Mp, 3072, 1024, nullptr,
                                             qb, kb, kTb, vTb);

        // 2) per-chunk KV outer products (MFMA) -> ST[e][d], z[d]
        chunk_kv<<<dim3(NCHUNKc / 4, BHp), 256, 0, stream>>>(kTb, vTb, S, z);

        // 3) exclusive prefix over chunks
        prefix_chunks<<<dim3(17, BHp), 256, 0, stream>>>(S, z);

        // 4) per-chunk attention output (MFMA)
        chunk_out<<<dim3(NCHUNKc, BHp), 256, 0, stream>>>(qb, kb, vTb, S, z, attb);

        // 5) output projection
        dim3 g3(1024 / 128, Mp / 128);
        gemm_bf16<0><<<g3, 256, 0, stream>>>(attb, woutb, Mp, 1024, 1024,
                                             out + (size_t)b0 * 4096 * 1024,
                                             nullptr, nullptr, nullptr, nullptr);
    }
}

// Round 9
// 444.263 us; speedup vs baseline: 1.0871x; 1.0871x over previous
//
#include <hip/hip_runtime.h>
#include <hip/hip_bf16.h>
#include <math.h>

#define B_SZc    4
#define L_SEQc   4096
#define EPSc     1e-6f
#define CHUNKc   128
#define NCHUNKc  32

// per-batch element counts
#define QKV_PER_B  4194304ull        // 16*4096*64
#define ATT_PER_B  4194304ull
#define X_PER_B    4194304ull
#define S_PER_B    2097152ull        // 16*32*64*64
#define Z_PER_B    32768ull

typedef __attribute__((ext_vector_type(8))) short s16x8;
typedef __attribute__((ext_vector_type(4))) short s16x4;
typedef __attribute__((ext_vector_type(4))) float f32x4;

__device__ __forceinline__ float phi_f(float x) {
    return x > 0.0f ? x + 1.0f : expf(x);   // elu(x)+1
}
__device__ __forceinline__ float bf2f(short h) {
    return __uint_as_float(((unsigned int)(unsigned short)h) << 16);
}
__device__ __forceinline__ short f2bf(float f) {
    unsigned int u = __float_as_uint(f);
    u = (u + 0x7FFFu + ((u >> 16) & 1u)) >> 16;   // RNE
    return (short)u;
}

#define GLOAD16(ldsp, gp) \
    __builtin_amdgcn_global_load_lds((const __attribute__((address_space(1))) void*)(gp), \
                                     (__attribute__((address_space(3))) void*)(ldsp), 16, 0, 0)

// ---------------------------------------------------------------------------
__global__ __launch_bounds__(256)
void cvt_f32_bf16(const float* __restrict__ in, short* __restrict__ out, int n)
{
    int i = (blockIdx.x * 256 + threadIdx.x) * 4;
    const int stride = gridDim.x * 256 * 4;
    for (; i < n; i += stride) {
        float4 v = *(const float4*)(in + i);
        short4 o = {f2bf(v.x), f2bf(v.y), f2bf(v.z), f2bf(v.w)};
        *(short4*)(out + i) = o;
    }
}

// ---------------------------------------------------------------------------
// bf16 MFMA GEMM NT (m97 structure), natural block order (swizzle reverted —
// measured +24MB FETCH in R8).
// MODE 0: C fp32 row-major (16 KB LDS).
// MODE 1: qkv scatter via ONE-SHOT LDS-staged epilogue (33 KB LDS):
//   whole 128x128 tile staged once (accs die immediately), then vectorized
//   q/k row stores and kT/vT transposed stores.
// ---------------------------------------------------------------------------
template<int MODE>
__global__ __launch_bounds__(256)
void gemm_bf16(const short* __restrict__ A, const short* __restrict__ Bm,
               int M, int N, int K, float* __restrict__ C,
               short* __restrict__ qb, short* __restrict__ kb,
               short* __restrict__ kTb, short* __restrict__ vTb)
{
    constexpr int SMEM_SHORTS = (MODE == 1) ? 128 * 132 : 8192;
    __shared__ __align__(16) short smem[SMEM_SHORTS];
    short* lA = smem;
    short* lB = smem + 4096;

    const int tid = threadIdx.x;
    const int lane = tid & 63;
    const int wave = tid >> 6;
    const int wr = wave >> 1, wc = wave & 1;
    const int bm = blockIdx.y, bn = blockIdx.x;

    const short* Abase = A + (size_t)bm * 128 * K;
    const short* Bbase = Bm + (size_t)bn * 128 * K;

    f32x4 acc[4][4];
#pragma unroll
    for (int i = 0; i < 4; ++i)
#pragma unroll
        for (int j = 0; j < 4; ++j) acc[i][j] = (f32x4){0.f, 0.f, 0.f, 0.f};

    const int lr = lane & 15;
    const int lk = (lane >> 4) * 8;
    const int cr0 = (lane >> 4) * 4;

    for (int k0 = 0; k0 < K; k0 += 32) {
#pragma unroll
        for (int c2 = 0; c2 < 2; ++c2) {
            const int idx = c2 * 256 + tid;
            const int row = idx >> 2;
            const int ks  = (idx & 3) * 8;
            GLOAD16(&lA[idx * 8], Abase + (size_t)row * K + k0 + ks);
            GLOAD16(&lB[idx * 8], Bbase + (size_t)row * K + k0 + ks);
        }
        __syncthreads();
        s16x8 af[4], bf[4];
#pragma unroll
        for (int m = 0; m < 4; ++m)
            af[m] = *(const s16x8*)&lA[(wr * 64 + m * 16 + lr) * 32 + lk];
#pragma unroll
        for (int n = 0; n < 4; ++n)
            bf[n] = *(const s16x8*)&lB[(wc * 64 + n * 16 + lr) * 32 + lk];
#pragma unroll
        for (int m = 0; m < 4; ++m)
#pragma unroll
            for (int n = 0; n < 4; ++n)
                acc[m][n] = __builtin_amdgcn_mfma_f32_16x16x32_bf16(af[m], bf[n], acc[m][n], 0, 0, 0);
        __syncthreads();
    }

    if (MODE == 0) {
#pragma unroll
        for (int m = 0; m < 4; ++m)
#pragma unroll
            for (int n = 0; n < 4; ++n) {
                const int col = bn * 128 + wc * 64 + n * 16 + lr;
#pragma unroll
                for (int j = 0; j < 4; ++j) {
                    const int row = bm * 128 + wr * 64 + m * 16 + cr0 + j;
                    C[(size_t)row * N + col] = acc[m][n][j];
                }
            }
    } else {
        // -------- one-shot LDS-staged scatter epilogue --------
        const int which = bn >> 3;             // 0=q, 1=k, 2=v (block-uniform)
        const int b = bm >> 5;                 // pass-local batch
        const int l_base = (bm & 31) * 128;

        // stage whole tile (accs die here)
#pragma unroll
        for (int m = 0; m < 4; ++m)
#pragma unroll
            for (int n = 0; n < 4; ++n) {
                const int cc = wc * 64 + n * 16 + lr;
#pragma unroll
                for (int j = 0; j < 4; ++j) {
                    float v = acc[m][n][j];
                    if (which < 2) v = phi_f(v);
                    smem[(wr * 64 + m * 16 + cr0 + j) * 132 + cc] = f2bf(v);
                }
            }
        __syncthreads();

        if (which < 2) {
            // q/k row-major: thread = (row, col-half); 8 x b128 reads + 8 x 16B stores
            short* dst0 = (which == 0) ? qb : kb;
            const int r = tid >> 1;
            const int half = tid & 1;
            const int gcol = bn * 128 + half * 64;
            const int h = (gcol >> 6) & 15;
            short* base = dst0 + ((size_t)(b * 16 + h) * 4096 + l_base + r) * 64;
#pragma unroll
            for (int w = 0; w < 8; ++w) {
                s16x8 vv = *(const s16x8*)&smem[r * 132 + half * 64 + w * 8];
                *(s16x8*)(base + w * 8) = vv;
            }
        }
        if (which >= 1) {
            // kT/vT transposed: thread = (col-lane, l-group); b16 column reads
            short* dstT = (which == 1) ? kTb : vTb;
            const int ls = tid & 15;           // l-group (8 rows each)
            const int dl = tid >> 4;           // col base 0..15
#pragma unroll
            for (int rep = 0; rep < 8; ++rep) {
                const int col = dl + rep * 16;
                const int gcol = bn * 128 + col;
                const int h = (gcol >> 6) & 15;
                const int d = gcol & 63;
                s16x8 vv;
#pragma unroll
                for (int i = 0; i < 8; ++i) vv[i] = smem[(ls * 8 + i) * 132 + col];
                *(s16x8*)(dstT + ((size_t)(b * 16 + h) * 64 + d) * 4096 + l_base + ls * 8) = vv;
            }
        }
    }
}

// ---------------------------------------------------------------------------
// Phase A (MFMA): per (bh, chunk): ST[e][d] = sum_t v[t][e]*k[t][d]; z[d].
// ---------------------------------------------------------------------------
__global__ __launch_bounds__(256)
void chunk_kv(const short* __restrict__ kTb, const short* __restrict__ vTb,
              float* __restrict__ ST, float* __restrict__ z)
{
    const int wave = threadIdx.x >> 6;
    const int lane = threadIdx.x & 63;
    const int c = blockIdx.x * 4 + wave;
    const int bh = blockIdx.y;
    const short* kT = kTb + (size_t)bh * 64 * 4096 + c * CHUNKc;
    const short* vT = vTb + (size_t)bh * 64 * 4096 + c * CHUNKc;
    const int lr = lane & 15;
    const int lk = (lane >> 4) * 8;

    f32x4 acc[4][4];
    f32x4 accz[4];
#pragma unroll
    for (int m = 0; m < 4; ++m) {
        accz[m] = (f32x4){0.f, 0.f, 0.f, 0.f};
#pragma unroll
        for (int n = 0; n < 4; ++n) acc[m][n] = (f32x4){0.f, 0.f, 0.f, 0.f};
    }
    s16x8 ones;
#pragma unroll
    for (int j = 0; j < 8; ++j) ones[j] = (short)0x3F80;

#pragma unroll
    for (int ks = 0; ks < 4; ++ks) {
        const int t0 = ks * 32 + lk;
        s16x8 a[4], b[4];
#pragma unroll
        for (int m = 0; m < 4; ++m)
            a[m] = *(const s16x8*)(vT + (size_t)(m * 16 + lr) * 4096 + t0);
#pragma unroll
        for (int n = 0; n < 4; ++n)
            b[n] = *(const s16x8*)(kT + (size_t)(n * 16 + lr) * 4096 + t0);
#pragma unroll
        for (int m = 0; m < 4; ++m)
#pragma unroll
            for (int n = 0; n < 4; ++n)
                acc[m][n] = __builtin_amdgcn_mfma_f32_16x16x32_bf16(a[m], b[n], acc[m][n], 0, 0, 0);
#pragma unroll
        for (int n = 0; n < 4; ++n)
            accz[n] = __builtin_amdgcn_mfma_f32_16x16x32_bf16(ones, b[n], accz[n], 0, 0, 0);
    }

    float* STc = ST + ((size_t)bh * NCHUNKc + c) * 4096;
    const int er0 = (lane >> 4) * 4;
#pragma unroll
    for (int m = 0; m < 4; ++m)
#pragma unroll
        for (int n = 0; n < 4; ++n)
#pragma unroll
            for (int j = 0; j < 4; ++j)
                STc[(m * 16 + er0 + j) * 64 + n * 16 + lr] = acc[m][n][j];
    if (lane < 16) {
        float* zc = z + ((size_t)bh * NCHUNKc + c) * 64;
#pragma unroll
        for (int n = 0; n < 4; ++n) zc[n * 16 + lane] = accz[n][0];
    }
}

// ---------------------------------------------------------------------------
__global__ __launch_bounds__(256)
void prefix_chunks(float* __restrict__ ST, float* __restrict__ z)
{
    const int sec = blockIdx.x, bh = blockIdx.y;
    const int tid = threadIdx.x;
    if (sec < 16) {
        float* base = ST + (size_t)bh * NCHUNKc * 4096 + sec * 256 + tid;
        float acc = 0.0f;
#pragma unroll
        for (int c = 0; c < NCHUNKc; ++c) {
            float t = base[(size_t)c * 4096];
            base[(size_t)c * 4096] = acc;
            acc += t;
        }
    } else if (tid < 64) {
        float* base = z + (size_t)bh * NCHUNKc * 64 + tid;
        float acc = 0.0f;
#pragma unroll
        for (int c = 0; c < NCHUNKc; ++c) {
            float t = base[c * 64];
            base[c * 64] = acc;
            acc += t;
        }
    }
}

// ---------------------------------------------------------------------------
// Phase C (MFMA): P = causal(QK^T) -> LDS fp32; den = rowsum(P)+q.z_pre;
// num = P@V + Q@(S_hi+S_lo); att = num/den.
// ---------------------------------------------------------------------------
__global__ __launch_bounds__(256)
void chunk_out(const short* __restrict__ qb, const short* __restrict__ kb,
               const short* __restrict__ vTb, const float* __restrict__ ST,
               const float* __restrict__ z, short* __restrict__ attb)
{
    const int c = blockIdx.x, bh = blockIdx.y;
    const int b = bh >> 4, h = bh & 15;
    const short* qc = qb + ((size_t)bh * L_SEQc + c * CHUNKc) * 64;
    const short* kc = kb + ((size_t)bh * L_SEQc + c * CHUNKc) * 64;
    const short* vT = vTb + (size_t)bh * 64 * 4096 + c * CHUNKc;
    const float* STp = ST + ((size_t)bh * NCHUNKc + c) * 4096;
    const float* zp  = z + ((size_t)bh * NCHUNKc + c) * 64;

    __shared__ float P[128][130];
    __shared__ float den_s[128];

    const int tid = threadIdx.x;
    const int lane = tid & 63;
    const int wave = tid >> 6;
    const int wr = wave >> 1, wc = wave & 1;
    const int lr = lane & 15;
    const int lg = lane >> 4;
    const int lk = lg * 8;
    const int cr0 = lg * 4;

    // ---- Phase 1: P = QK^T, causal mask, fp32 -> LDS ----
    {
        f32x4 p[4][4];
#pragma unroll
        for (int m = 0; m < 4; ++m)
#pragma unroll
            for (int n = 0; n < 4; ++n) p[m][n] = (f32x4){0.f, 0.f, 0.f, 0.f};
#pragma unroll
        for (int ks = 0; ks < 2; ++ks) {
            s16x8 a[4], bfr[4];
#pragma unroll
            for (int m = 0; m < 4; ++m)
                a[m] = *(const s16x8*)(qc + (size_t)(wr * 64 + m * 16 + lr) * 64 + ks * 32 + lk);
#pragma unroll
            for (int n = 0; n < 4; ++n)
                bfr[n] = *(const s16x8*)(kc + (size_t)(wc * 64 + n * 16 + lr) * 64 + ks * 32 + lk);
#pragma unroll
            for (int m = 0; m < 4; ++m)
#pragma unroll
                for (int n = 0; n < 4; ++n)
                    p[m][n] = __builtin_amdgcn_mfma_f32_16x16x32_bf16(a[m], bfr[n], p[m][n], 0, 0, 0);
        }
#pragma unroll
        for (int m = 0; m < 4; ++m)
#pragma unroll
            for (int n = 0; n < 4; ++n) {
                const int cc = wc * 64 + n * 16 + lr;
#pragma unroll
                for (int j = 0; j < 4; ++j) {
                    const int r = wr * 64 + m * 16 + cr0 + j;
                    P[r][cc] = (cc <= r) ? p[m][n][j] : 0.0f;
                }
            }
    }
    __syncthreads();

    // ---- Phase 2: den ----
    {
        const int r = tid >> 1;
        const int half = tid & 1;
        float s = 0.0f;
        const float* Pr = &P[r][half * 64];
#pragma unroll
        for (int t = 0; t < 64; t += 2) {
            float2 v2 = *(const float2*)&Pr[t];
            s += v2.x + v2.y;
        }
        const short* qr = qc + r * 64 + half * 32;
        const float* zh = zp + half * 32;
#pragma unroll
        for (int d0 = 0; d0 < 32; d0 += 8) {
            s16x8 qv = *(const s16x8*)(qr + d0);
#pragma unroll
            for (int j = 0; j < 8; ++j) s += bf2f(qv[j]) * zh[d0 + j];
        }
        s += __shfl_xor(s, 1);
        if (half == 0) den_s[r] = fmaxf(s, EPSc);
    }
    __syncthreads();

    // ---- Phase 3: num = P @ V^T + Q @ (S_hi + S_lo) ----
    f32x4 num[4][2];
#pragma unroll
    for (int m = 0; m < 4; ++m)
#pragma unroll
        for (int n = 0; n < 2; ++n) num[m][n] = (f32x4){0.f, 0.f, 0.f, 0.f};

#pragma unroll
    for (int ks = 0; ks < 4; ++ks) {
        const int t0 = ks * 32 + lk;
        s16x8 a[4];
#pragma unroll
        for (int m = 0; m < 4; ++m) {
            const float* pr = &P[wr * 64 + m * 16 + lr][t0];
            float2 f0 = *(const float2*)&pr[0];
            float2 f1 = *(const float2*)&pr[2];
            float2 f2 = *(const float2*)&pr[4];
            float2 f3 = *(const float2*)&pr[6];
            s16x8 av;
            av[0] = f2bf(f0.x); av[1] = f2bf(f0.y);
            av[2] = f2bf(f1.x); av[3] = f2bf(f1.y);
            av[4] = f2bf(f2.x); av[5] = f2bf(f2.y);
            av[6] = f2bf(f3.x); av[7] = f2bf(f3.y);
            a[m] = av;
        }
#pragma unroll
        for (int n = 0; n < 2; ++n) {
            s16x8 bv = *(const s16x8*)(vT + (size_t)(wc * 32 + n * 16 + lr) * 4096 + t0);
#pragma unroll
            for (int m = 0; m < 4; ++m)
                num[m][n] = __builtin_amdgcn_mfma_f32_16x16x32_bf16(a[m], bv, num[m][n], 0, 0, 0);
        }
    }

#pragma unroll
    for (int kk = 0; kk < 2; ++kk) {
        s16x8 qa[4];
#pragma unroll
        for (int m = 0; m < 4; ++m)
            qa[m] = *(const s16x8*)(qc + (size_t)(wr * 64 + m * 16 + lr) * 64 + kk * 32 + lk);
#pragma unroll
        for (int n = 0; n < 2; ++n) {
            const float* sp = STp + (size_t)(wc * 32 + n * 16 + lr) * 64 + kk * 32 + lk;
            float4 s0 = *(const float4*)sp;
            float4 s1 = *(const float4*)(sp + 4);
            float sv[8] = {s0.x, s0.y, s0.z, s0.w, s1.x, s1.y, s1.z, s1.w};
            s16x8 bhi, blo;
#pragma unroll
            for (int j = 0; j < 8; ++j) {
                short hi = f2bf(sv[j]);
                bhi[j] = hi;
                blo[j] = f2bf(sv[j] - bf2f(hi));
            }
#pragma unroll
            for (int m = 0; m < 4; ++m) {
                num[m][n] = __builtin_amdgcn_mfma_f32_16x16x32_bf16(qa[m], bhi, num[m][n], 0, 0, 0);
                num[m][n] = __builtin_amdgcn_mfma_f32_16x16x32_bf16(qa[m], blo, num[m][n], 0, 0, 0);
            }
        }
    }

#pragma unroll
    for (int m = 0; m < 4; ++m)
#pragma unroll
        for (int n = 0; n < 2; ++n) {
            const int e = wc * 32 + n * 16 + lr;
#pragma unroll
            for (int j = 0; j < 4; ++j) {
                const int r = wr * 64 + m * 16 + cr0 + j;
                const float inv = 1.0f / den_s[r];
                attb[((size_t)(b * 4096 + c * CHUNKc + r)) * 1024 + h * 64 + e] =
                    f2bf(num[m][n][j] * inv);
            }
        }
}

// ---------------------------------------------------------------------------
extern "C" void kernel_launch(void* const* d_in, const int* in_sizes, int n_in,
                              void* d_out, int out_size, void* d_ws, size_t ws_size,
                              hipStream_t stream) {
    const float* x     = (const float*)d_in[0];
    const float* w_qkv = (const float*)d_in[1];
    const float* w_out = (const float*)d_in[2];
    float* out = (float*)d_out;

    const size_t fixedB = 2ull * (3072 * 1024 + 1024 * 1024);
    const size_t perB_real = 2ull * X_PER_B + 2ull * 4 * QKV_PER_B + 2ull * ATT_PER_B
                           + 4ull * S_PER_B + 4ull * Z_PER_B;
    int Bp = 1;
    if (ws_size >= fixedB + 4 * perB_real + 65536) Bp = 4;
    else if (ws_size >= fixedB + 2 * perB_real + 65536) Bp = 2;

    char* p = (char*)d_ws;
    short* wqkvb = (short*)p; p += 2ull * 3072 * 1024;
    short* woutb = (short*)p; p += 2ull * 1024 * 1024;
    short* xb    = (short*)p; p += 2ull * X_PER_B * Bp;
    short* qb    = (short*)p; p += 2ull * QKV_PER_B * Bp;
    short* kb    = (short*)p; p += 2ull * QKV_PER_B * Bp;
    short* kTb   = (short*)p; p += 2ull * QKV_PER_B * Bp;
    short* vTb   = (short*)p; p += 2ull * QKV_PER_B * Bp;
    short* attb  = (short*)p; p += 2ull * ATT_PER_B * Bp;
    float* S     = (float*)p; p += 4ull * S_PER_B * Bp;
    float* z     = (float*)p;

    const int Mp = Bp * 4096;
    const int BHp = Bp * 16;

    cvt_f32_bf16<<<dim3(1024), 256, 0, stream>>>(w_qkv, wqkvb, 3072 * 1024);
    cvt_f32_bf16<<<dim3(512), 256, 0, stream>>>(w_out, woutb, 1024 * 1024);

    for (int b0 = 0; b0 < B_SZc; b0 += Bp) {
        const float* xp = x + (size_t)b0 * 4096 * 1024;

        cvt_f32_bf16<<<dim3(2048), 256, 0, stream>>>(xp, xb, Mp * 1024);

        // 1) QKV projection + phi + scatter (q, k, kT, vT)
        dim3 g1(3072 / 128, Mp / 128);
        gemm_bf16<1><<<g1, 256, 0, stream>>>(xb, wqkvb, Mp, 3072, 1024, nullptr,
                                             qb, kb, kTb, vTb);

        // 2) per-chunk KV outer products (MFMA) -> ST[e][d], z[d]
        chunk_kv<<<dim3(NCHUNKc / 4, BHp), 256, 0, stream>>>(kTb, vTb, S, z);

        // 3) exclusive prefix over chunks
        prefix_chunks<<<dim3(17, BHp), 256, 0, stream>>>(S, z);

        // 4) per-chunk attention output (MFMA)
        chunk_out<<<dim3(NCHUNKc, BHp), 256, 0, stream>>>(qb, kb, vTb, S, z, attb);

        // 5) output projection
        dim3 g3(1024 / 128, Mp / 128);
        gemm_bf16<0><<<g3, 256, 0, stream>>>(attb, woutb, Mp, 1024, 1024,
                                             out + (size_t)b0 * 4096 * 1024,
                                             nullptr, nullptr, nullptr, nullptr);
    }
}